// Round 1
// baseline (389.250 us; speedup 1.0000x reference)
//
#include <hip/hip_runtime.h>
#include <hip/hip_bf16.h>
#include <stdint.h>

// ---------------------------------------------------------------------------
// GCN on MI355X: 3x (dense GEMM -> spmm -> bias [-> relu -> concat])
// fp16 activations/weights, fp32 accumulation everywhere.
// ---------------------------------------------------------------------------

typedef _Float16 half8 __attribute__((ext_vector_type(8)));
typedef _Float16 half4 __attribute__((ext_vector_type(4)));
typedef float    f32x4 __attribute__((ext_vector_type(4)));

#define N_NODES 10000
#define M_PAD   10112   // 79 * 128
#define N_EDGES 320000

// ---------------------------------------------------------------------------
// fp32 -> fp16 elementwise convert (vector x4)
// ---------------------------------------------------------------------------
__global__ void conv_f32_f16(const float* __restrict__ in,
                             _Float16* __restrict__ out, int n4) {
    int i = blockIdx.x * blockDim.x + threadIdx.x;
    if (i < n4) {
        f32x4 v = *(const f32x4*)(in + (size_t)i * 4);
        half4 h;
        h[0] = (_Float16)v[0]; h[1] = (_Float16)v[1];
        h[2] = (_Float16)v[2]; h[3] = (_Float16)v[3];
        *(half4*)(out + (size_t)i * 4) = h;
    }
}

// fp32 [K x Nc] -> fp16 transposed [Nc x K]
__global__ void transpose_f32_f16(const float* __restrict__ W,
                                  _Float16* __restrict__ Wt, int K, int Nc) {
    int i = blockIdx.x * blockDim.x + threadIdx.x;
    if (i < K * Nc) {
        int k = i / Nc;
        int n = i - k * Nc;
        Wt[(size_t)n * K + k] = (_Float16)W[i];
    }
}

// ---------------------------------------------------------------------------
// CSR build
// ---------------------------------------------------------------------------
__global__ void zero_int(int* __restrict__ p, int n) {
    int i = blockIdx.x * blockDim.x + threadIdx.x;
    if (i < n) p[i] = 0;
}

__global__ void hist_rows(const int* __restrict__ rows, int* __restrict__ counts, int E) {
    int i = blockIdx.x * blockDim.x + threadIdx.x;
    if (i < E) atomicAdd(&counts[rows[i]], 1);
}

// single block, 256 threads: exclusive scan of counts -> row_ptr, cursor
__global__ void scan_rowptr(const int* __restrict__ counts,
                            int* __restrict__ row_ptr,
                            int* __restrict__ cursor, int n, int E) {
    __shared__ int part[256];
    const int t = threadIdx.x;
    const int chunk = (n + 255) / 256;
    const int lo = t * chunk;
    const int hi = min(n, lo + chunk);
    int s = 0;
    for (int i = lo; i < hi; ++i) s += counts[i];
    part[t] = s;
    __syncthreads();
    if (t == 0) {
        int run = 0;
        for (int i = 0; i < 256; ++i) { int v = part[i]; part[i] = run; run += v; }
    }
    __syncthreads();
    int run = part[t];
    for (int i = lo; i < hi; ++i) {
        row_ptr[i] = run;
        cursor[i]  = run;
        run += counts[i];
    }
    if (t == 0) row_ptr[n] = E;
}

__global__ void scatter_edges(const int* __restrict__ rows,
                              const int* __restrict__ cols,
                              const float* __restrict__ vals,
                              int* __restrict__ cursor,
                              int* __restrict__ col_s,
                              float* __restrict__ val_s, int E) {
    int i = blockIdx.x * blockDim.x + threadIdx.x;
    if (i < E) {
        int r = rows[i];
        int p = atomicAdd(&cursor[r], 1);
        col_s[p] = cols[i];
        val_s[p] = vals[i];
    }
}

// ---------------------------------------------------------------------------
// GEMM: C[M_PAD x Nc] = A[M_PAD x K] * B[K x Nc], B given transposed (Bt[Nc x K]).
// fp16 in, fp16 out, fp32 MFMA accumulate. 128x128 tile, BK=32,
// 4 waves (2x2), each wave 4x4 tiles of 16x16x32 MFMA.
// ---------------------------------------------------------------------------
__global__ __launch_bounds__(256) void gemm_f16(
    const _Float16* __restrict__ A,
    const _Float16* __restrict__ Bt,
    _Float16* __restrict__ C,
    int K, int Nc)
{
    __shared__ _Float16 As[128 * 32];
    __shared__ _Float16 Bs[128 * 32];

    const int t    = threadIdx.x;
    const int lane = t & 63;
    const int wid  = t >> 6;
    const int wrow = wid >> 1;      // 0..1
    const int wcol = wid & 1;       // 0..1
    const int quad = lane >> 4;     // 0..3
    const int l15  = lane & 15;

    const int rowBase = blockIdx.y * 128;
    const int colBase = blockIdx.x * 128;

    f32x4 acc[4][4];
#pragma unroll
    for (int m = 0; m < 4; ++m)
#pragma unroll
        for (int n = 0; n < 4; ++n)
            acc[m][n] = (f32x4){0.f, 0.f, 0.f, 0.f};

    for (int k0 = 0; k0 < K; k0 += 32) {
        // stage A-tile [128x32] and Bt-tile [128x32] (both k-contiguous)
#pragma unroll
        for (int p = 0; p < 2; ++p) {
            int linear = t + p * 256;          // 0..511
            int r = linear >> 2;               // 0..127
            int c = (linear & 3) << 3;         // 0,8,16,24
            *(f32x4*)(&As[r * 32 + c]) =
                *(const f32x4*)(&A[(size_t)(rowBase + r) * K + k0 + c]);
            *(f32x4*)(&Bs[r * 32 + c]) =
                *(const f32x4*)(&Bt[(size_t)(colBase + r) * K + k0 + c]);
        }
        __syncthreads();

        half8 af[4], bf[4];
#pragma unroll
        for (int m = 0; m < 4; ++m)
            af[m] = *(const half8*)(&As[(wrow * 64 + m * 16 + l15) * 32 + quad * 8]);
#pragma unroll
        for (int n = 0; n < 4; ++n)
            bf[n] = *(const half8*)(&Bs[(wcol * 64 + n * 16 + l15) * 32 + quad * 8]);

#pragma unroll
        for (int m = 0; m < 4; ++m)
#pragma unroll
            for (int n = 0; n < 4; ++n)
                acc[m][n] = __builtin_amdgcn_mfma_f32_16x16x32_f16(
                    af[m], bf[n], acc[m][n], 0, 0, 0);
        __syncthreads();
    }

    // epilogue: C/D layout col = lane&15, row = quad*4 + reg
#pragma unroll
    for (int m = 0; m < 4; ++m) {
#pragma unroll
        for (int n = 0; n < 4; ++n) {
            int col = colBase + wcol * 64 + n * 16 + l15;
#pragma unroll
            for (int r = 0; r < 4; ++r) {
                int row = rowBase + wrow * 64 + m * 16 + quad * 4 + r;
                C[(size_t)row * Nc + col] = (_Float16)acc[m][n][r];
            }
        }
    }
}

// ---------------------------------------------------------------------------
// SpMM fused: out[r] = sum_e val*S[col] + bias, then (relu, concat) or fp32 out.
// One wave per row; lane holds D/64 features.
// ---------------------------------------------------------------------------
template <int D, bool FINAL>
__global__ __launch_bounds__(256) void spmm_fused(
    const int* __restrict__ row_ptr,
    const int* __restrict__ col_s,
    const float* __restrict__ val_s,
    const _Float16* __restrict__ S,     // [M_PAD x D]
    const float* __restrict__ bias,     // [D]
    _Float16* __restrict__ Hout,        // [M_PAD x 2D] if !FINAL
    float* __restrict__ Fout)           // [N_NODES x D] if FINAL
{
    const int w = (blockIdx.x * blockDim.x + threadIdx.x) >> 6;
    if (w >= N_NODES) return;
    const int lane = threadIdx.x & 63;
    constexpr int V = D / 64;

    float acc[V];
#pragma unroll
    for (int j = 0; j < V; ++j) acc[j] = 0.f;

    const int e1 = row_ptr[w + 1];
    for (int e = row_ptr[w]; e < e1; ++e) {
        const int c  = col_s[e];
        const float v = val_s[e];
        if constexpr (V == 8) {
            half8 sv = *(const half8*)(S + (size_t)c * D + lane * 8);
#pragma unroll
            for (int j = 0; j < 8; ++j) acc[j] += v * (float)sv[j];
        } else {
            half4 sv = *(const half4*)(S + (size_t)c * D + lane * 4);
#pragma unroll
            for (int j = 0; j < 4; ++j) acc[j] += v * (float)sv[j];
        }
    }

    if constexpr (FINAL) {
#pragma unroll
        for (int j = 0; j < V; ++j) {
            float s = acc[j] + bias[lane * V + j];
            Fout[(size_t)w * D + lane * V + j] = s;
        }
    } else {
#pragma unroll
        for (int j = 0; j < V; ++j) {
            float s = acc[j] + bias[lane * V + j];
            float r = s > 0.f ? s : 0.f;
            Hout[(size_t)w * (2 * D) + lane * V + j]     = (_Float16)r;
            Hout[(size_t)w * (2 * D) + D + lane * V + j] = (_Float16)s;
        }
    }
}

// ---------------------------------------------------------------------------
static inline char* alignp(char* p, size_t a) {
    return (char*)(((uintptr_t)p + a - 1) & ~(uintptr_t)(a - 1));
}

extern "C" void kernel_launch(void* const* d_in, const int* in_sizes, int n_in,
                              void* d_out, int out_size, void* d_ws, size_t ws_size,
                              hipStream_t stream) {
    const float* x        = (const float*)d_in[0];   // [10000 x 512]
    const int*   edge_row = (const int*)d_in[1];     // [E]
    const int*   edge_col = (const int*)d_in[2];     // [E]
    const float* edge_val = (const float*)d_in[3];   // [E]
    const float* W0 = (const float*)d_in[4];         // [512 x 512]
    const float* W1 = (const float*)d_in[5];         // [1024 x 512]
    const float* W2 = (const float*)d_in[6];         // [1024 x 256]
    const float* b0 = (const float*)d_in[7];
    const float* b1 = (const float*)d_in[8];
    const float* b2 = (const float*)d_in[9];
    float* out = (float*)d_out;                      // [10000 x 256]

    const int E = N_EDGES;

    // ---- workspace carve-up ----
    char* p = (char*)d_ws;
    _Float16* Xh  = (_Float16*)alignp(p, 256);  p = (char*)(Xh  + (size_t)M_PAD * 512);
    _Float16* S   = (_Float16*)alignp(p, 256);  p = (char*)(S   + (size_t)M_PAD * 512);   // S0/S1/S2
    _Float16* H   = (_Float16*)alignp(p, 256);  p = (char*)(H   + (size_t)M_PAD * 1024);  // H1/H2
    _Float16* W0t = (_Float16*)alignp(p, 256);  p = (char*)(W0t + (size_t)512 * 512);
    _Float16* W1t = (_Float16*)alignp(p, 256);  p = (char*)(W1t + (size_t)512 * 1024);
    _Float16* W2t = (_Float16*)alignp(p, 256);  p = (char*)(W2t + (size_t)256 * 1024);
    int*   counts  = (int*)alignp(p, 256);      p = (char*)(counts  + N_NODES);
    int*   row_ptr = (int*)alignp(p, 256);      p = (char*)(row_ptr + N_NODES + 1);
    int*   cursor  = (int*)alignp(p, 256);      p = (char*)(cursor  + N_NODES);
    int*   col_s   = (int*)alignp(p, 256);      p = (char*)(col_s   + E);
    float* val_s   = (float*)alignp(p, 256);    p = (char*)(val_s   + E);

    // ---- conversions ----
    {
        int n4 = (N_NODES * 512) / 4;
        conv_f32_f16<<<(n4 + 255) / 256, 256, 0, stream>>>(x, Xh, n4);
        transpose_f32_f16<<<(512 * 512 + 255) / 256, 256, 0, stream>>>(W0, W0t, 512, 512);
        transpose_f32_f16<<<(1024 * 512 + 255) / 256, 256, 0, stream>>>(W1, W1t, 1024, 512);
        transpose_f32_f16<<<(1024 * 256 + 255) / 256, 256, 0, stream>>>(W2, W2t, 1024, 256);
    }

    // ---- CSR build ----
    zero_int<<<(N_NODES + 255) / 256, 256, 0, stream>>>(counts, N_NODES);
    hist_rows<<<(E + 255) / 256, 256, 0, stream>>>(edge_row, counts, E);
    scan_rowptr<<<1, 256, 0, stream>>>(counts, row_ptr, cursor, N_NODES, E);
    scatter_edges<<<(E + 255) / 256, 256, 0, stream>>>(edge_row, edge_col, edge_val,
                                                       cursor, col_s, val_s, E);

    const int spmm_blocks = (N_NODES + 3) / 4;   // 4 waves (rows) per 256-thr block

    // ---- layer 0 ----
    gemm_f16<<<dim3(512 / 128, M_PAD / 128), 256, 0, stream>>>(Xh, W0t, S, 512, 512);
    spmm_fused<512, false><<<spmm_blocks, 256, 0, stream>>>(row_ptr, col_s, val_s,
                                                            S, b0, H, nullptr);
    // ---- layer 1 ----
    gemm_f16<<<dim3(512 / 128, M_PAD / 128), 256, 0, stream>>>(H, W1t, S, 1024, 512);
    spmm_fused<512, false><<<spmm_blocks, 256, 0, stream>>>(row_ptr, col_s, val_s,
                                                            S, b1, H, nullptr);
    // ---- layer 2 ----
    gemm_f16<<<dim3(256 / 128, M_PAD / 128), 256, 0, stream>>>(H, W2t, S, 1024, 256);
    spmm_fused<256, true><<<spmm_blocks, 256, 0, stream>>>(row_ptr, col_s, val_s,
                                                           S, b2, nullptr, out);
}

// Round 2
// 329.010 us; speedup vs baseline: 1.1831x; 1.1831x over previous
//
#include <hip/hip_runtime.h>
#include <hip/hip_bf16.h>
#include <stdint.h>
#include <type_traits>

// ---------------------------------------------------------------------------
// GCN on MI355X: 3x (dense GEMM -> spmm -> bias [-> relu -> concat])
// fp16 activations/weights, fp32 accumulation everywhere.
// R2: spmm edge-loop unroll x4 (gather ILP), GEMM staging via
//     global_load_lds width=16, prep kernels fused into one.
// ---------------------------------------------------------------------------

typedef _Float16 half8 __attribute__((ext_vector_type(8)));
typedef _Float16 half4 __attribute__((ext_vector_type(4)));
typedef float    f32x4 __attribute__((ext_vector_type(4)));

#define N_NODES 10000
#define M_PAD   10112   // 79 * 128
#define N_EDGES 320000

__device__ __forceinline__ void async16(const void* g, void* l) {
    __builtin_amdgcn_global_load_lds(
        (const __attribute__((address_space(1))) void*)g,
        (__attribute__((address_space(3))) void*)l, 16, 0, 0);
}

// ---------------------------------------------------------------------------
// prep: x fp32->fp16, three weight transposes (fp32 [K x Nc] -> fp16 [Nc x K]),
// zero counts. One kernel, segmented by linear thread id.
// ---------------------------------------------------------------------------
#define PREP_A  1280000                   // x: 10000*512/4 threads, 4 elems each
#define PREP_B  (512 * 512)               // W0t
#define PREP_C  (1024 * 512)              // W1t
#define PREP_D  (1024 * 256)              // W2t
#define PREP_E  N_NODES                   // zero counts
#define PREP_TOTAL (PREP_A + PREP_B + PREP_C + PREP_D + PREP_E)

__global__ void prep(const float* __restrict__ x,  _Float16* __restrict__ Xh,
                     const float* __restrict__ W0, _Float16* __restrict__ W0t,
                     const float* __restrict__ W1, _Float16* __restrict__ W1t,
                     const float* __restrict__ W2, _Float16* __restrict__ W2t,
                     int* __restrict__ counts) {
    int i = blockIdx.x * blockDim.x + threadIdx.x;
    if (i < PREP_A) {
        f32x4 v = *(const f32x4*)(x + (size_t)i * 4);
        half4 h;
        h[0] = (_Float16)v[0]; h[1] = (_Float16)v[1];
        h[2] = (_Float16)v[2]; h[3] = (_Float16)v[3];
        *(half4*)(Xh + (size_t)i * 4) = h;
        return;
    }
    i -= PREP_A;
    if (i < PREP_B) {                       // W0: 512x512
        int n = i >> 9, k = i & 511;        // i = n*512 + k (output index)
        W0t[i] = (_Float16)W0[(size_t)k * 512 + n];
        return;
    }
    i -= PREP_B;
    if (i < PREP_C) {                       // W1: 1024x512 -> W1t 512x1024
        int n = i >> 10, k = i & 1023;
        W1t[i] = (_Float16)W1[(size_t)k * 512 + n];
        return;
    }
    i -= PREP_C;
    if (i < PREP_D) {                       // W2: 1024x256 -> W2t 256x1024
        int n = i >> 10, k = i & 1023;
        W2t[i] = (_Float16)W2[(size_t)k * 256 + n];
        return;
    }
    i -= PREP_D;
    if (i < PREP_E) counts[i] = 0;
}

// ---------------------------------------------------------------------------
// CSR build
// ---------------------------------------------------------------------------
__global__ void hist_rows(const int* __restrict__ rows, int* __restrict__ counts, int E) {
    int i = blockIdx.x * blockDim.x + threadIdx.x;
    if (i < E) atomicAdd(&counts[rows[i]], 1);
}

// single block, 256 threads: exclusive scan of counts -> row_ptr, cursor
__global__ void scan_rowptr(const int* __restrict__ counts,
                            int* __restrict__ row_ptr,
                            int* __restrict__ cursor, int n, int E) {
    __shared__ int part[256];
    const int t = threadIdx.x;
    const int chunk = (n + 255) / 256;
    const int lo = t * chunk;
    const int hi = min(n, lo + chunk);
    int s = 0;
    for (int i = lo; i < hi; ++i) s += counts[i];
    part[t] = s;
    __syncthreads();
    if (t == 0) {
        int run = 0;
        for (int i = 0; i < 256; ++i) { int v = part[i]; part[i] = run; run += v; }
    }
    __syncthreads();
    int run = part[t];
    for (int i = lo; i < hi; ++i) {
        row_ptr[i] = run;
        cursor[i]  = run;
        run += counts[i];
    }
    if (t == 0) row_ptr[n] = E;
}

__global__ void scatter_edges(const int* __restrict__ rows,
                              const int* __restrict__ cols,
                              const float* __restrict__ vals,
                              int* __restrict__ cursor,
                              int* __restrict__ col_s,
                              float* __restrict__ val_s, int E) {
    int i = blockIdx.x * blockDim.x + threadIdx.x;
    if (i < E) {
        int r = rows[i];
        int p = atomicAdd(&cursor[r], 1);
        col_s[p] = cols[i];
        val_s[p] = vals[i];
    }
}

// ---------------------------------------------------------------------------
// GEMM: C[M_PAD x Nc] = A[M_PAD x K] * Bt[Nc x K]^T. fp16 in/out, fp32 acc.
// 128x128 tile, BK=32, 4 waves (2x2), each wave 4x4 tiles of 16x16x32 MFMA.
// Staging via global_load_lds dwordx4 (wave-uniform LDS base + lane*16).
// ---------------------------------------------------------------------------
__global__ __launch_bounds__(256) void gemm_f16(
    const _Float16* __restrict__ A,
    const _Float16* __restrict__ Bt,
    _Float16* __restrict__ C,
    int K, int Nc)
{
    __shared__ _Float16 As[128 * 32];   // 8 KB, row-major [r][k]
    __shared__ _Float16 Bs[128 * 32];

    const int t    = threadIdx.x;
    const int lane = t & 63;
    const int wid  = t >> 6;
    const int wrow = wid >> 1;      // 0..1
    const int wcol = wid & 1;       // 0..1
    const int quad = lane >> 4;     // 0..3
    const int l15  = lane & 15;

    const int rowBase = blockIdx.y * 128;
    const int colBase = blockIdx.x * 128;

    // staging: wave wid stages chunks q = wid*2+p (p=0,1); chunk q = rows
    // [16q,16q+16) x 32 halves. lane i -> row 16q + i/4, half-col (i&3)*8.
    // LDS offset of lane i's 16 B = q*1024 + i*16  (As + q*512 halves).
    const int rIn = lane >> 2;            // 0..15 within chunk
    const int cIn = (lane & 3) * 8;       // halves

    f32x4 acc[4][4];
#pragma unroll
    for (int m = 0; m < 4; ++m)
#pragma unroll
        for (int n = 0; n < 4; ++n)
            acc[m][n] = (f32x4){0.f, 0.f, 0.f, 0.f};

    for (int k0 = 0; k0 < K; k0 += 32) {
#pragma unroll
        for (int p = 0; p < 2; ++p) {
            const int q = wid * 2 + p;
            const int r = q * 16 + rIn;
            async16(&A[(size_t)(rowBase + r) * K + k0 + cIn], &As[q * 512]);
            async16(&Bt[(size_t)(colBase + r) * K + k0 + cIn], &Bs[q * 512]);
        }
        __syncthreads();

        half8 af[4], bf[4];
#pragma unroll
        for (int m = 0; m < 4; ++m)
            af[m] = *(const half8*)(&As[(wrow * 64 + m * 16 + l15) * 32 + quad * 8]);
#pragma unroll
        for (int n = 0; n < 4; ++n)
            bf[n] = *(const half8*)(&Bs[(wcol * 64 + n * 16 + l15) * 32 + quad * 8]);

#pragma unroll
        for (int m = 0; m < 4; ++m)
#pragma unroll
            for (int n = 0; n < 4; ++n)
                acc[m][n] = __builtin_amdgcn_mfma_f32_16x16x32_f16(
                    af[m], bf[n], acc[m][n], 0, 0, 0);
        __syncthreads();
    }

    // epilogue: C/D layout col = lane&15, row = quad*4 + reg
#pragma unroll
    for (int m = 0; m < 4; ++m) {
#pragma unroll
        for (int n = 0; n < 4; ++n) {
            int col = colBase + wcol * 64 + n * 16 + l15;
#pragma unroll
            for (int r = 0; r < 4; ++r) {
                int row = rowBase + wrow * 64 + m * 16 + quad * 4 + r;
                C[(size_t)row * Nc + col] = (_Float16)acc[m][n][r];
            }
        }
    }
}

// ---------------------------------------------------------------------------
// SpMM fused: out[r] = sum_e val*S[col] + bias, then (relu, concat) or fp32 out.
// One wave per row; lane holds D/64 features. Edge loop unrolled x4 so four
// independent 16B-per-lane gathers are in flight (latency -> BW bound).
// ---------------------------------------------------------------------------
template <int D, bool FINAL>
__global__ __launch_bounds__(256) void spmm_fused(
    const int* __restrict__ row_ptr,
    const int* __restrict__ col_s,
    const float* __restrict__ val_s,
    const _Float16* __restrict__ S,     // [M_PAD x D]
    const float* __restrict__ bias,     // [D]
    _Float16* __restrict__ Hout,        // [M_PAD x 2D] if !FINAL
    float* __restrict__ Fout)           // [N_NODES x D] if FINAL
{
    const int w = (blockIdx.x * blockDim.x + threadIdx.x) >> 6;
    if (w >= N_NODES) return;
    const int lane = threadIdx.x & 63;
    constexpr int V = D / 64;
    using hv = std::conditional_t<V == 8, half8, half4>;

    float acc[V];
#pragma unroll
    for (int j = 0; j < V; ++j) acc[j] = 0.f;

    const _Float16* __restrict__ Sl = S + lane * V;

    int e = row_ptr[w];
    const int e1 = row_ptr[w + 1];

    for (; e + 4 <= e1; e += 4) {
        const int c0 = col_s[e], c1 = col_s[e + 1], c2 = col_s[e + 2], c3 = col_s[e + 3];
        const float v0 = val_s[e], v1 = val_s[e + 1], v2 = val_s[e + 2], v3 = val_s[e + 3];
        hv s0 = *(const hv*)(Sl + (size_t)c0 * D);
        hv s1 = *(const hv*)(Sl + (size_t)c1 * D);
        hv s2 = *(const hv*)(Sl + (size_t)c2 * D);
        hv s3 = *(const hv*)(Sl + (size_t)c3 * D);
#pragma unroll
        for (int j = 0; j < V; ++j) {
            acc[j] += v0 * (float)s0[j];
            acc[j] += v1 * (float)s1[j];
            acc[j] += v2 * (float)s2[j];
            acc[j] += v3 * (float)s3[j];
        }
    }
    for (; e < e1; ++e) {
        const int c = col_s[e];
        const float v = val_s[e];
        hv sv = *(const hv*)(Sl + (size_t)c * D);
#pragma unroll
        for (int j = 0; j < V; ++j) acc[j] += v * (float)sv[j];
    }

    if constexpr (FINAL) {
#pragma unroll
        for (int j = 0; j < V; ++j) {
            float s = acc[j] + bias[lane * V + j];
            Fout[(size_t)w * D + lane * V + j] = s;
        }
    } else {
#pragma unroll
        for (int j = 0; j < V; ++j) {
            float s = acc[j] + bias[lane * V + j];
            float r = s > 0.f ? s : 0.f;
            Hout[(size_t)w * (2 * D) + lane * V + j]     = (_Float16)r;
            Hout[(size_t)w * (2 * D) + D + lane * V + j] = (_Float16)s;
        }
    }
}

// ---------------------------------------------------------------------------
static inline char* alignp(char* p, size_t a) {
    return (char*)(((uintptr_t)p + a - 1) & ~(uintptr_t)(a - 1));
}

extern "C" void kernel_launch(void* const* d_in, const int* in_sizes, int n_in,
                              void* d_out, int out_size, void* d_ws, size_t ws_size,
                              hipStream_t stream) {
    const float* x        = (const float*)d_in[0];   // [10000 x 512]
    const int*   edge_row = (const int*)d_in[1];     // [E]
    const int*   edge_col = (const int*)d_in[2];     // [E]
    const float* edge_val = (const float*)d_in[3];   // [E]
    const float* W0 = (const float*)d_in[4];         // [512 x 512]
    const float* W1 = (const float*)d_in[5];         // [1024 x 512]
    const float* W2 = (const float*)d_in[6];         // [1024 x 256]
    const float* b0 = (const float*)d_in[7];
    const float* b1 = (const float*)d_in[8];
    const float* b2 = (const float*)d_in[9];
    float* out = (float*)d_out;                      // [10000 x 256]

    const int E = N_EDGES;

    // ---- workspace carve-up ----
    char* p = (char*)d_ws;
    _Float16* Xh  = (_Float16*)alignp(p, 256);  p = (char*)(Xh  + (size_t)M_PAD * 512);
    _Float16* S   = (_Float16*)alignp(p, 256);  p = (char*)(S   + (size_t)M_PAD * 512);   // S0/S1/S2
    _Float16* H   = (_Float16*)alignp(p, 256);  p = (char*)(H   + (size_t)M_PAD * 1024);  // H1/H2
    _Float16* W0t = (_Float16*)alignp(p, 256);  p = (char*)(W0t + (size_t)512 * 512);
    _Float16* W1t = (_Float16*)alignp(p, 256);  p = (char*)(W1t + (size_t)512 * 1024);
    _Float16* W2t = (_Float16*)alignp(p, 256);  p = (char*)(W2t + (size_t)256 * 1024);
    int*   counts  = (int*)alignp(p, 256);      p = (char*)(counts  + N_NODES);
    int*   row_ptr = (int*)alignp(p, 256);      p = (char*)(row_ptr + N_NODES + 1);
    int*   cursor  = (int*)alignp(p, 256);      p = (char*)(cursor  + N_NODES);
    int*   col_s   = (int*)alignp(p, 256);      p = (char*)(col_s   + E);
    float* val_s   = (float*)alignp(p, 256);    p = (char*)(val_s   + E);

    // ---- prep (conv + transposes + zero counts), then CSR build ----
    prep<<<(PREP_TOTAL + 255) / 256, 256, 0, stream>>>(x, Xh, W0, W0t, W1, W1t,
                                                       W2, W2t, counts);
    hist_rows<<<(E + 255) / 256, 256, 0, stream>>>(edge_row, counts, E);
    scan_rowptr<<<1, 256, 0, stream>>>(counts, row_ptr, cursor, N_NODES, E);
    scatter_edges<<<(E + 255) / 256, 256, 0, stream>>>(edge_row, edge_col, edge_val,
                                                       cursor, col_s, val_s, E);

    const int spmm_blocks = (N_NODES + 3) / 4;   // 4 waves (rows) per 256-thr block

    // ---- layer 0 ----
    gemm_f16<<<dim3(512 / 128, M_PAD / 128), 256, 0, stream>>>(Xh, W0t, S, 512, 512);
    spmm_fused<512, false><<<spmm_blocks, 256, 0, stream>>>(row_ptr, col_s, val_s,
                                                            S, b0, H, nullptr);
    // ---- layer 1 ----
    gemm_f16<<<dim3(512 / 128, M_PAD / 128), 256, 0, stream>>>(H, W1t, S, 1024, 512);
    spmm_fused<512, false><<<spmm_blocks, 256, 0, stream>>>(row_ptr, col_s, val_s,
                                                            S, b1, H, nullptr);
    // ---- layer 2 ----
    gemm_f16<<<dim3(256 / 128, M_PAD / 128), 256, 0, stream>>>(H, W2t, S, 1024, 256);
    spmm_fused<256, true><<<spmm_blocks, 256, 0, stream>>>(row_ptr, col_s, val_s,
                                                           S, b2, nullptr, out);
}

// Round 3
// 322.639 us; speedup vs baseline: 1.2065x; 1.0197x over previous
//
#include <hip/hip_runtime.h>
#include <hip/hip_bf16.h>
#include <stdint.h>
#include <type_traits>

// ---------------------------------------------------------------------------
// GCN on MI355X: 3x (dense GEMM -> spmm -> bias [-> relu -> concat])
// fp16 activations/weights, fp32 accumulation everywhere.
// R3: spmm = block-per-row, 4 waves split the row's edges, LDS reduce
//     (40000 waves of gather parallelism); packed (col,val) float2 edges.
// ---------------------------------------------------------------------------

typedef _Float16 half8 __attribute__((ext_vector_type(8)));
typedef _Float16 half4 __attribute__((ext_vector_type(4)));
typedef float    f32x4 __attribute__((ext_vector_type(4)));

#define N_NODES 10000
#define M_PAD   10112   // 79 * 128
#define N_EDGES 320000

__device__ __forceinline__ void async16(const void* g, void* l) {
    __builtin_amdgcn_global_load_lds(
        (const __attribute__((address_space(1))) void*)g,
        (__attribute__((address_space(3))) void*)l, 16, 0, 0);
}

// ---------------------------------------------------------------------------
// prep: x fp32->fp16, three weight transposes (fp32 [K x Nc] -> fp16 [Nc x K]),
// zero counts. One kernel, segmented by linear thread id.
// ---------------------------------------------------------------------------
#define PREP_A  1280000                   // x: 10000*512/4 threads, 4 elems each
#define PREP_B  (512 * 512)               // W0t
#define PREP_C  (1024 * 512)              // W1t
#define PREP_D  (1024 * 256)              // W2t
#define PREP_E  N_NODES                   // zero counts
#define PREP_TOTAL (PREP_A + PREP_B + PREP_C + PREP_D + PREP_E)

__global__ void prep(const float* __restrict__ x,  _Float16* __restrict__ Xh,
                     const float* __restrict__ W0, _Float16* __restrict__ W0t,
                     const float* __restrict__ W1, _Float16* __restrict__ W1t,
                     const float* __restrict__ W2, _Float16* __restrict__ W2t,
                     int* __restrict__ counts) {
    int i = blockIdx.x * blockDim.x + threadIdx.x;
    if (i < PREP_A) {
        f32x4 v = *(const f32x4*)(x + (size_t)i * 4);
        half4 h;
        h[0] = (_Float16)v[0]; h[1] = (_Float16)v[1];
        h[2] = (_Float16)v[2]; h[3] = (_Float16)v[3];
        *(half4*)(Xh + (size_t)i * 4) = h;
        return;
    }
    i -= PREP_A;
    if (i < PREP_B) {                       // W0: 512x512
        int n = i >> 9, k = i & 511;
        W0t[i] = (_Float16)W0[(size_t)k * 512 + n];
        return;
    }
    i -= PREP_B;
    if (i < PREP_C) {                       // W1: 1024x512 -> W1t 512x1024
        int n = i >> 10, k = i & 1023;
        W1t[i] = (_Float16)W1[(size_t)k * 512 + n];
        return;
    }
    i -= PREP_C;
    if (i < PREP_D) {                       // W2: 1024x256 -> W2t 256x1024
        int n = i >> 10, k = i & 1023;
        W2t[i] = (_Float16)W2[(size_t)k * 256 + n];
        return;
    }
    i -= PREP_D;
    if (i < PREP_E) counts[i] = 0;
}

// ---------------------------------------------------------------------------
// CSR build
// ---------------------------------------------------------------------------
__global__ void hist_rows(const int* __restrict__ rows, int* __restrict__ counts, int E) {
    int i = blockIdx.x * blockDim.x + threadIdx.x;
    if (i < E) atomicAdd(&counts[rows[i]], 1);
}

// single block, 256 threads: exclusive scan of counts -> row_ptr, cursor
__global__ void scan_rowptr(const int* __restrict__ counts,
                            int* __restrict__ row_ptr,
                            int* __restrict__ cursor, int n, int E) {
    __shared__ int part[256];
    const int t = threadIdx.x;
    const int chunk = (n + 255) / 256;
    const int lo = t * chunk;
    const int hi = min(n, lo + chunk);
    int s = 0;
    for (int i = lo; i < hi; ++i) s += counts[i];
    part[t] = s;
    __syncthreads();
    if (t == 0) {
        int run = 0;
        for (int i = 0; i < 256; ++i) { int v = part[i]; part[i] = run; run += v; }
    }
    __syncthreads();
    int run = part[t];
    for (int i = lo; i < hi; ++i) {
        row_ptr[i] = run;
        cursor[i]  = run;
        run += counts[i];
    }
    if (t == 0) row_ptr[n] = E;
}

// packed edge record: {col as int bits, val}
__global__ void scatter_edges(const int* __restrict__ rows,
                              const int* __restrict__ cols,
                              const float* __restrict__ vals,
                              int* __restrict__ cursor,
                              float2* __restrict__ ev, int E) {
    int i = blockIdx.x * blockDim.x + threadIdx.x;
    if (i < E) {
        int r = rows[i];
        int p = atomicAdd(&cursor[r], 1);
        ev[p] = make_float2(__int_as_float(cols[i]), vals[i]);
    }
}

// ---------------------------------------------------------------------------
// GEMM: C[M_PAD x Nc] = A[M_PAD x K] * Bt[Nc x K]^T. fp16 in/out, fp32 acc.
// 128x128 tile, BK=32, 4 waves (2x2), each wave 4x4 tiles of 16x16x32 MFMA.
// Staging via global_load_lds dwordx4 (wave-uniform LDS base + lane*16).
// ---------------------------------------------------------------------------
__global__ __launch_bounds__(256) void gemm_f16(
    const _Float16* __restrict__ A,
    const _Float16* __restrict__ Bt,
    _Float16* __restrict__ C,
    int K, int Nc)
{
    __shared__ _Float16 As[128 * 32];   // 8 KB, row-major [r][k]
    __shared__ _Float16 Bs[128 * 32];

    const int t    = threadIdx.x;
    const int lane = t & 63;
    const int wid  = t >> 6;
    const int wrow = wid >> 1;      // 0..1
    const int wcol = wid & 1;       // 0..1
    const int quad = lane >> 4;     // 0..3
    const int l15  = lane & 15;

    const int rowBase = blockIdx.y * 128;
    const int colBase = blockIdx.x * 128;

    const int rIn = lane >> 2;            // 0..15 within chunk
    const int cIn = (lane & 3) * 8;       // halves

    f32x4 acc[4][4];
#pragma unroll
    for (int m = 0; m < 4; ++m)
#pragma unroll
        for (int n = 0; n < 4; ++n)
            acc[m][n] = (f32x4){0.f, 0.f, 0.f, 0.f};

    for (int k0 = 0; k0 < K; k0 += 32) {
#pragma unroll
        for (int p = 0; p < 2; ++p) {
            const int q = wid * 2 + p;
            const int r = q * 16 + rIn;
            async16(&A[(size_t)(rowBase + r) * K + k0 + cIn], &As[q * 512]);
            async16(&Bt[(size_t)(colBase + r) * K + k0 + cIn], &Bs[q * 512]);
        }
        __syncthreads();

        half8 af[4], bf[4];
#pragma unroll
        for (int m = 0; m < 4; ++m)
            af[m] = *(const half8*)(&As[(wrow * 64 + m * 16 + l15) * 32 + quad * 8]);
#pragma unroll
        for (int n = 0; n < 4; ++n)
            bf[n] = *(const half8*)(&Bs[(wcol * 64 + n * 16 + l15) * 32 + quad * 8]);

#pragma unroll
        for (int m = 0; m < 4; ++m)
#pragma unroll
            for (int n = 0; n < 4; ++n)
                acc[m][n] = __builtin_amdgcn_mfma_f32_16x16x32_f16(
                    af[m], bf[n], acc[m][n], 0, 0, 0);
        __syncthreads();
    }

    // epilogue: C/D layout col = lane&15, row = quad*4 + reg
#pragma unroll
    for (int m = 0; m < 4; ++m) {
#pragma unroll
        for (int n = 0; n < 4; ++n) {
            int col = colBase + wcol * 64 + n * 16 + l15;
#pragma unroll
            for (int r = 0; r < 4; ++r) {
                int row = rowBase + wrow * 64 + m * 16 + quad * 4 + r;
                C[(size_t)row * Nc + col] = (_Float16)acc[m][n][r];
            }
        }
    }
}

// ---------------------------------------------------------------------------
// SpMM fused, block-per-row: 4 waves split the row's edges, each gathers
// full-width (D) rows of S with fp32 accumulation; partials reduced in LDS,
// then bias (+relu+concat) or fp32 final store.
// ---------------------------------------------------------------------------
template <int D, bool FINAL>
__global__ __launch_bounds__(256) void spmm_block(
    const int* __restrict__ row_ptr,
    const float2* __restrict__ ev,
    const _Float16* __restrict__ S,     // [M_PAD x D]
    const float* __restrict__ bias,     // [D]
    _Float16* __restrict__ Hout,        // [M_PAD x 2D] if !FINAL
    float* __restrict__ Fout)           // [N_NODES x D] if FINAL
{
    const int w    = blockIdx.x;
    const int t    = threadIdx.x;
    const int lane = t & 63;
    const int q    = t >> 6;            // wave 0..3
    constexpr int V = D / 64;
    using hv = std::conditional_t<V == 8, half8, half4>;

    __shared__ float part[4][D];

    const int r0  = row_ptr[w];
    const int deg = row_ptr[w + 1] - r0;
    const int c0  = r0 + (deg * q) / 4;
    const int c1  = r0 + (deg * (q + 1)) / 4;

    float acc[V];
#pragma unroll
    for (int j = 0; j < V; ++j) acc[j] = 0.f;

    const _Float16* __restrict__ Sl = S + lane * V;

    int e = c0;
    for (; e + 4 <= c1; e += 4) {
        float2 p0 = ev[e], p1 = ev[e + 1], p2 = ev[e + 2], p3 = ev[e + 3];
        hv s0 = *(const hv*)(Sl + (size_t)__float_as_int(p0.x) * D);
        hv s1 = *(const hv*)(Sl + (size_t)__float_as_int(p1.x) * D);
        hv s2 = *(const hv*)(Sl + (size_t)__float_as_int(p2.x) * D);
        hv s3 = *(const hv*)(Sl + (size_t)__float_as_int(p3.x) * D);
#pragma unroll
        for (int j = 0; j < V; ++j) {
            acc[j] += p0.y * (float)s0[j];
            acc[j] += p1.y * (float)s1[j];
            acc[j] += p2.y * (float)s2[j];
            acc[j] += p3.y * (float)s3[j];
        }
    }
    for (; e < c1; ++e) {
        float2 p0 = ev[e];
        hv sv = *(const hv*)(Sl + (size_t)__float_as_int(p0.x) * D);
#pragma unroll
        for (int j = 0; j < V; ++j) acc[j] += p0.y * (float)sv[j];
    }

#pragma unroll
    for (int j = 0; j < V; ++j) part[q][lane * V + j] = acc[j];
    __syncthreads();

    // reduce + epilogue: D/256 features per thread
    constexpr int F = D / 256;          // 2 (D=512) or 1 (D=256)
#pragma unroll
    for (int i = 0; i < F; ++i) {
        const int f = t * F + i;
        float s = part[0][f] + part[1][f] + part[2][f] + part[3][f] + bias[f];
        if constexpr (FINAL) {
            Fout[(size_t)w * D + f] = s;
        } else {
            float r = s > 0.f ? s : 0.f;
            Hout[(size_t)w * (2 * D) + f]     = (_Float16)r;
            Hout[(size_t)w * (2 * D) + D + f] = (_Float16)s;
        }
    }
}

// ---------------------------------------------------------------------------
static inline char* alignp(char* p, size_t a) {
    return (char*)(((uintptr_t)p + a - 1) & ~(uintptr_t)(a - 1));
}

extern "C" void kernel_launch(void* const* d_in, const int* in_sizes, int n_in,
                              void* d_out, int out_size, void* d_ws, size_t ws_size,
                              hipStream_t stream) {
    const float* x        = (const float*)d_in[0];   // [10000 x 512]
    const int*   edge_row = (const int*)d_in[1];     // [E]
    const int*   edge_col = (const int*)d_in[2];     // [E]
    const float* edge_val = (const float*)d_in[3];   // [E]
    const float* W0 = (const float*)d_in[4];         // [512 x 512]
    const float* W1 = (const float*)d_in[5];         // [1024 x 512]
    const float* W2 = (const float*)d_in[6];         // [1024 x 256]
    const float* b0 = (const float*)d_in[7];
    const float* b1 = (const float*)d_in[8];
    const float* b2 = (const float*)d_in[9];
    float* out = (float*)d_out;                      // [10000 x 256]

    const int E = N_EDGES;

    // ---- workspace carve-up ----
    char* p = (char*)d_ws;
    _Float16* Xh  = (_Float16*)alignp(p, 256);  p = (char*)(Xh  + (size_t)M_PAD * 512);
    _Float16* S   = (_Float16*)alignp(p, 256);  p = (char*)(S   + (size_t)M_PAD * 512);
    _Float16* H   = (_Float16*)alignp(p, 256);  p = (char*)(H   + (size_t)M_PAD * 1024);
    _Float16* W0t = (_Float16*)alignp(p, 256);  p = (char*)(W0t + (size_t)512 * 512);
    _Float16* W1t = (_Float16*)alignp(p, 256);  p = (char*)(W1t + (size_t)512 * 1024);
    _Float16* W2t = (_Float16*)alignp(p, 256);  p = (char*)(W2t + (size_t)256 * 1024);
    int*    counts  = (int*)alignp(p, 256);     p = (char*)(counts  + N_NODES);
    int*    row_ptr = (int*)alignp(p, 256);     p = (char*)(row_ptr + N_NODES + 1);
    int*    cursor  = (int*)alignp(p, 256);     p = (char*)(cursor  + N_NODES);
    float2* ev      = (float2*)alignp(p, 256);  p = (char*)(ev      + E);

    // ---- prep (conv + transposes + zero counts), then CSR build ----
    prep<<<(PREP_TOTAL + 255) / 256, 256, 0, stream>>>(x, Xh, W0, W0t, W1, W1t,
                                                       W2, W2t, counts);
    hist_rows<<<(E + 255) / 256, 256, 0, stream>>>(edge_row, counts, E);
    scan_rowptr<<<1, 256, 0, stream>>>(counts, row_ptr, cursor, N_NODES, E);
    scatter_edges<<<(E + 255) / 256, 256, 0, stream>>>(edge_row, edge_col, edge_val,
                                                       cursor, ev, E);

    // ---- layer 0 ----
    gemm_f16<<<dim3(512 / 128, M_PAD / 128), 256, 0, stream>>>(Xh, W0t, S, 512, 512);
    spmm_block<512, false><<<N_NODES, 256, 0, stream>>>(row_ptr, ev, S, b0, H, nullptr);
    // ---- layer 1 ----
    gemm_f16<<<dim3(512 / 128, M_PAD / 128), 256, 0, stream>>>(H, W1t, S, 1024, 512);
    spmm_block<512, false><<<N_NODES, 256, 0, stream>>>(row_ptr, ev, S, b1, H, nullptr);
    // ---- layer 2 ----
    gemm_f16<<<dim3(256 / 128, M_PAD / 128), 256, 0, stream>>>(H, W2t, S, 1024, 256);
    spmm_block<256, true><<<N_NODES, 256, 0, stream>>>(row_ptr, ev, S, b2, nullptr, out);
}

// Round 4
// 316.889 us; speedup vs baseline: 1.2284x; 1.0181x over previous
//
#include <hip/hip_runtime.h>
#include <hip/hip_bf16.h>
#include <stdint.h>
#include <type_traits>

// ---------------------------------------------------------------------------
// GCN on MI355X: 3x (dense GEMM -> spmm -> bias [-> relu -> concat])
// fp16 activations/weights, fp32 accumulation everywhere.
// R4: GEMM K-loop double-buffered (1 barrier/k-step, prefetch covers vmcnt
//     drain at low occupancy); spmm = 2 rows/block x 2 waves/row, unroll 8.
// ---------------------------------------------------------------------------

typedef _Float16 half8 __attribute__((ext_vector_type(8)));
typedef _Float16 half4 __attribute__((ext_vector_type(4)));
typedef float    f32x4 __attribute__((ext_vector_type(4)));
typedef float    f32x2 __attribute__((ext_vector_type(2)));

#define N_NODES 10000
#define M_PAD   10112   // 79 * 128
#define N_EDGES 320000

__device__ __forceinline__ void async16(const void* g, void* l) {
    __builtin_amdgcn_global_load_lds(
        (const __attribute__((address_space(1))) void*)g,
        (__attribute__((address_space(3))) void*)l, 16, 0, 0);
}

// ---------------------------------------------------------------------------
// prep: x fp32->fp16, three weight transposes (fp32 [K x Nc] -> fp16 [Nc x K]),
// zero counts. One kernel, segmented by linear thread id.
// ---------------------------------------------------------------------------
#define PREP_A  1280000                   // x: 10000*512/4 threads, 4 elems each
#define PREP_B  (512 * 512)               // W0t
#define PREP_C  (1024 * 512)              // W1t
#define PREP_D  (1024 * 256)              // W2t
#define PREP_E  N_NODES                   // zero counts
#define PREP_TOTAL (PREP_A + PREP_B + PREP_C + PREP_D + PREP_E)

__global__ void prep(const float* __restrict__ x,  _Float16* __restrict__ Xh,
                     const float* __restrict__ W0, _Float16* __restrict__ W0t,
                     const float* __restrict__ W1, _Float16* __restrict__ W1t,
                     const float* __restrict__ W2, _Float16* __restrict__ W2t,
                     int* __restrict__ counts) {
    int i = blockIdx.x * blockDim.x + threadIdx.x;
    if (i < PREP_A) {
        f32x4 v = *(const f32x4*)(x + (size_t)i * 4);
        half4 h;
        h[0] = (_Float16)v[0]; h[1] = (_Float16)v[1];
        h[2] = (_Float16)v[2]; h[3] = (_Float16)v[3];
        *(half4*)(Xh + (size_t)i * 4) = h;
        return;
    }
    i -= PREP_A;
    if (i < PREP_B) {                       // W0: 512x512
        int n = i >> 9, k = i & 511;
        W0t[i] = (_Float16)W0[(size_t)k * 512 + n];
        return;
    }
    i -= PREP_B;
    if (i < PREP_C) {                       // W1: 1024x512 -> W1t 512x1024
        int n = i >> 10, k = i & 1023;
        W1t[i] = (_Float16)W1[(size_t)k * 512 + n];
        return;
    }
    i -= PREP_C;
    if (i < PREP_D) {                       // W2: 1024x256 -> W2t 256x1024
        int n = i >> 10, k = i & 1023;
        W2t[i] = (_Float16)W2[(size_t)k * 256 + n];
        return;
    }
    i -= PREP_D;
    if (i < PREP_E) counts[i] = 0;
}

// ---------------------------------------------------------------------------
// CSR build
// ---------------------------------------------------------------------------
__global__ void hist_rows(const int* __restrict__ rows, int* __restrict__ counts, int E) {
    int i = blockIdx.x * blockDim.x + threadIdx.x;
    if (i < E) atomicAdd(&counts[rows[i]], 1);
}

__global__ void scan_rowptr(const int* __restrict__ counts,
                            int* __restrict__ row_ptr,
                            int* __restrict__ cursor, int n, int E) {
    __shared__ int part[256];
    const int t = threadIdx.x;
    const int chunk = (n + 255) / 256;
    const int lo = t * chunk;
    const int hi = min(n, lo + chunk);
    int s = 0;
    for (int i = lo; i < hi; ++i) s += counts[i];
    part[t] = s;
    __syncthreads();
    if (t == 0) {
        int run = 0;
        for (int i = 0; i < 256; ++i) { int v = part[i]; part[i] = run; run += v; }
    }
    __syncthreads();
    int run = part[t];
    for (int i = lo; i < hi; ++i) {
        row_ptr[i] = run;
        cursor[i]  = run;
        run += counts[i];
    }
    if (t == 0) row_ptr[n] = E;
}

// packed edge record: {col as int bits, val}
__global__ void scatter_edges(const int* __restrict__ rows,
                              const int* __restrict__ cols,
                              const float* __restrict__ vals,
                              int* __restrict__ cursor,
                              float2* __restrict__ ev, int E) {
    int i = blockIdx.x * blockDim.x + threadIdx.x;
    if (i < E) {
        int r = rows[i];
        int p = atomicAdd(&cursor[r], 1);
        ev[p] = make_float2(__int_as_float(cols[i]), vals[i]);
    }
}

// ---------------------------------------------------------------------------
// GEMM: C[M_PAD x Nc] = A[M_PAD x K] * Bt[Nc x K]^T. fp16 in/out, fp32 acc.
// 128x128 tile, BK=32, 4 waves (2x2), each wave 4x4 tiles of 16x16x32 MFMA.
// Double-buffered LDS: one barrier per k-step; prefetch for step i+1 issues
// right after the barrier and is drained at the NEXT barrier (covered by
// the ds_read+MFMA phase) instead of stalling immediately.
// ---------------------------------------------------------------------------
__global__ __launch_bounds__(256) void gemm_f16_db(
    const _Float16* __restrict__ A,
    const _Float16* __restrict__ Bt,
    _Float16* __restrict__ C,
    int K, int Nc)
{
    __shared__ _Float16 As[2][128 * 32];   // 2 x 8 KB
    __shared__ _Float16 Bs[2][128 * 32];

    const int t    = threadIdx.x;
    const int lane = t & 63;
    const int wid  = t >> 6;
    const int wrow = wid >> 1;      // 0..1
    const int wcol = wid & 1;       // 0..1
    const int quad = lane >> 4;     // 0..3
    const int l15  = lane & 15;

    const int rowBase = blockIdx.y * 128;
    const int colBase = blockIdx.x * 128;

    const int rIn = lane >> 2;            // 0..15 within 16-row chunk
    const int cIn = (lane & 3) * 8;       // halves

    f32x4 acc[4][4];
#pragma unroll
    for (int m = 0; m < 4; ++m)
#pragma unroll
        for (int n = 0; n < 4; ++n)
            acc[m][n] = (f32x4){0.f, 0.f, 0.f, 0.f};

    auto stage = [&](int buf, int k0) {
#pragma unroll
        for (int p = 0; p < 2; ++p) {
            const int q = wid * 2 + p;            // wave-uniform chunk id
            const int r = q * 16 + rIn;
            async16(&A[(size_t)(rowBase + r) * K + k0 + cIn], &As[buf][q * 512]);
            async16(&Bt[(size_t)(colBase + r) * K + k0 + cIn], &Bs[buf][q * 512]);
        }
    };

    const int nk = K >> 5;
    stage(0, 0);

    for (int i = 0; i < nk; ++i) {
        __syncthreads();                          // drains stage(i); protects LDS
        if (i + 1 < nk) stage((i + 1) & 1, (i + 1) << 5);

        const int b = i & 1;
        half8 af[4], bf[4];
#pragma unroll
        for (int m = 0; m < 4; ++m)
            af[m] = *(const half8*)(&As[b][(wrow * 64 + m * 16 + l15) * 32 + quad * 8]);
#pragma unroll
        for (int n = 0; n < 4; ++n)
            bf[n] = *(const half8*)(&Bs[b][(wcol * 64 + n * 16 + l15) * 32 + quad * 8]);

#pragma unroll
        for (int m = 0; m < 4; ++m)
#pragma unroll
            for (int n = 0; n < 4; ++n)
                acc[m][n] = __builtin_amdgcn_mfma_f32_16x16x32_f16(
                    af[m], bf[n], acc[m][n], 0, 0, 0);
    }

    // epilogue: C/D layout col = lane&15, row = quad*4 + reg
#pragma unroll
    for (int m = 0; m < 4; ++m) {
#pragma unroll
        for (int n = 0; n < 4; ++n) {
            int col = colBase + wcol * 64 + n * 16 + l15;
#pragma unroll
            for (int r = 0; r < 4; ++r) {
                int row = rowBase + wrow * 64 + m * 16 + quad * 4 + r;
                C[(size_t)row * Nc + col] = (_Float16)acc[m][n][r];
            }
        }
    }
}

// ---------------------------------------------------------------------------
// SpMM fused: 2 rows per block, 2 waves per row (each ~deg/2 edges),
// unroll 8 -> 4 -> 1 for gather ILP; LDS reduce; fused bias(+relu+concat).
// ---------------------------------------------------------------------------
template <int D, bool FINAL>
__global__ __launch_bounds__(256) void spmm2(
    const int* __restrict__ row_ptr,
    const float2* __restrict__ ev,
    const _Float16* __restrict__ S,     // [M_PAD x D]
    const float* __restrict__ bias,     // [D]
    _Float16* __restrict__ Hout,        // [M_PAD x 2D] if !FINAL
    float* __restrict__ Fout)           // [N_NODES x D] if FINAL
{
    const int w0   = blockIdx.x * 2;
    const int t    = threadIdx.x;
    const int lane = t & 63;
    const int q    = t >> 6;            // wave 0..3
    const int row  = w0 + (q >> 1);
    const int half = q & 1;
    constexpr int V = D / 64;
    using hv = std::conditional_t<V == 8, half8, half4>;

    __shared__ float part[4][D];

    const int r0  = row_ptr[row];
    const int deg = row_ptr[row + 1] - r0;
    const int c0  = r0 + ((deg * half) >> 1);
    const int c1  = r0 + ((deg * (half + 1)) >> 1);

    float acc[V];
#pragma unroll
    for (int j = 0; j < V; ++j) acc[j] = 0.f;

    const _Float16* __restrict__ Sl = S + lane * V;

    int e = c0;
    for (; e + 8 <= c1; e += 8) {
        float2 p[8];
        hv     s[8];
#pragma unroll
        for (int u = 0; u < 8; ++u) p[u] = ev[e + u];
#pragma unroll
        for (int u = 0; u < 8; ++u)
            s[u] = *(const hv*)(Sl + (size_t)__float_as_int(p[u].x) * D);
#pragma unroll
        for (int u = 0; u < 8; ++u)
#pragma unroll
            for (int j = 0; j < V; ++j) acc[j] += p[u].y * (float)s[u][j];
    }
    for (; e + 4 <= c1; e += 4) {
        float2 p[4];
        hv     s[4];
#pragma unroll
        for (int u = 0; u < 4; ++u) p[u] = ev[e + u];
#pragma unroll
        for (int u = 0; u < 4; ++u)
            s[u] = *(const hv*)(Sl + (size_t)__float_as_int(p[u].x) * D);
#pragma unroll
        for (int u = 0; u < 4; ++u)
#pragma unroll
            for (int j = 0; j < V; ++j) acc[j] += p[u].y * (float)s[u][j];
    }
    for (; e < c1; ++e) {
        float2 p0 = ev[e];
        hv sv = *(const hv*)(Sl + (size_t)__float_as_int(p0.x) * D);
#pragma unroll
        for (int j = 0; j < V; ++j) acc[j] += p0.y * (float)sv[j];
    }

#pragma unroll
    for (int j = 0; j < V; ++j) part[q][lane * V + j] = acc[j];
    __syncthreads();

    // reduce + epilogue: threads 0..127 -> row w0, 128..255 -> row w0+1.
    constexpr int F = D / 128;          // feats per thread: 4 (D=512), 2 (D=256)
    const int r   = t >> 7;             // 0 or 1
    const int f0  = (t & 127) * F;
    const int wr  = w0 + r;
#pragma unroll
    for (int i = 0; i < F; ++i) {
        const int f = f0 + i;
        float s = part[2 * r][f] + part[2 * r + 1][f] + bias[f];
        if constexpr (FINAL) {
            Fout[(size_t)wr * D + f] = s;
        } else {
            float rl = s > 0.f ? s : 0.f;
            Hout[(size_t)wr * (2 * D) + f]     = (_Float16)rl;
            Hout[(size_t)wr * (2 * D) + D + f] = (_Float16)s;
        }
    }
}

// ---------------------------------------------------------------------------
static inline char* alignp(char* p, size_t a) {
    return (char*)(((uintptr_t)p + a - 1) & ~(uintptr_t)(a - 1));
}

extern "C" void kernel_launch(void* const* d_in, const int* in_sizes, int n_in,
                              void* d_out, int out_size, void* d_ws, size_t ws_size,
                              hipStream_t stream) {
    const float* x        = (const float*)d_in[0];   // [10000 x 512]
    const int*   edge_row = (const int*)d_in[1];     // [E]
    const int*   edge_col = (const int*)d_in[2];     // [E]
    const float* edge_val = (const float*)d_in[3];   // [E]
    const float* W0 = (const float*)d_in[4];         // [512 x 512]
    const float* W1 = (const float*)d_in[5];         // [1024 x 512]
    const float* W2 = (const float*)d_in[6];         // [1024 x 256]
    const float* b0 = (const float*)d_in[7];
    const float* b1 = (const float*)d_in[8];
    const float* b2 = (const float*)d_in[9];
    float* out = (float*)d_out;                      // [10000 x 256]

    const int E = N_EDGES;

    // ---- workspace carve-up ----
    char* p = (char*)d_ws;
    _Float16* Xh  = (_Float16*)alignp(p, 256);  p = (char*)(Xh  + (size_t)M_PAD * 512);
    _Float16* S   = (_Float16*)alignp(p, 256);  p = (char*)(S   + (size_t)M_PAD * 512);
    _Float16* H   = (_Float16*)alignp(p, 256);  p = (char*)(H   + (size_t)M_PAD * 1024);
    _Float16* W0t = (_Float16*)alignp(p, 256);  p = (char*)(W0t + (size_t)512 * 512);
    _Float16* W1t = (_Float16*)alignp(p, 256);  p = (char*)(W1t + (size_t)512 * 1024);
    _Float16* W2t = (_Float16*)alignp(p, 256);  p = (char*)(W2t + (size_t)256 * 1024);
    int*    counts  = (int*)alignp(p, 256);     p = (char*)(counts  + N_NODES);
    int*    row_ptr = (int*)alignp(p, 256);     p = (char*)(row_ptr + N_NODES + 1);
    int*    cursor  = (int*)alignp(p, 256);     p = (char*)(cursor  + N_NODES);
    float2* ev      = (float2*)alignp(p, 256);  p = (char*)(ev      + E);

    // ---- prep (conv + transposes + zero counts), then CSR build ----
    prep<<<(PREP_TOTAL + 255) / 256, 256, 0, stream>>>(x, Xh, W0, W0t, W1, W1t,
                                                       W2, W2t, counts);
    hist_rows<<<(E + 255) / 256, 256, 0, stream>>>(edge_row, counts, E);
    scan_rowptr<<<1, 256, 0, stream>>>(counts, row_ptr, cursor, N_NODES, E);
    scatter_edges<<<(E + 255) / 256, 256, 0, stream>>>(edge_row, edge_col, edge_val,
                                                       cursor, ev, E);

    // ---- layer 0 ----
    gemm_f16_db<<<dim3(512 / 128, M_PAD / 128), 256, 0, stream>>>(Xh, W0t, S, 512, 512);
    spmm2<512, false><<<N_NODES / 2, 256, 0, stream>>>(row_ptr, ev, S, b0, H, nullptr);
    // ---- layer 1 ----
    gemm_f16_db<<<dim3(512 / 128, M_PAD / 128), 256, 0, stream>>>(H, W1t, S, 1024, 512);
    spmm2<512, false><<<N_NODES / 2, 256, 0, stream>>>(row_ptr, ev, S, b1, H, nullptr);
    // ---- layer 2 ----
    gemm_f16_db<<<dim3(256 / 128, M_PAD / 128), 256, 0, stream>>>(H, W2t, S, 1024, 256);
    spmm2<256, true><<<N_NODES / 2, 256, 0, stream>>>(row_ptr, ev, S, b2, nullptr, out);
}

// Round 5
// 296.391 us; speedup vs baseline: 1.3133x; 1.0692x over previous
//
#include <hip/hip_runtime.h>
#include <hip/hip_bf16.h>
#include <stdint.h>
#include <type_traits>

// ---------------------------------------------------------------------------
// GCN on MI355X: 3x (dense GEMM -> spmm -> bias [-> relu -> concat])
// fp16 activations/weights, fp32 accumulation everywhere.
// R5: spmm feature-sliced (128-wide) so per-slice S fits 4MB per-XCD L2,
//     slice pinned to XCD via blockIdx%8; GEMM retiled 64x128 / 64x64
//     -> 632 blocks (2.5/CU) for co-resident-block latency hiding.
// ---------------------------------------------------------------------------

typedef _Float16 half8 __attribute__((ext_vector_type(8)));
typedef _Float16 half4 __attribute__((ext_vector_type(4)));
typedef float    f32x4 __attribute__((ext_vector_type(4)));

#define N_NODES 10000
#define M_PAD   10112   // 158 * 64
#define N_EDGES 320000

__device__ __forceinline__ void async16(const void* g, void* l) {
    __builtin_amdgcn_global_load_lds(
        (const __attribute__((address_space(1))) void*)g,
        (__attribute__((address_space(3))) void*)l, 16, 0, 0);
}

// ---------------------------------------------------------------------------
// prep: x fp32->fp16, three weight transposes (fp32 [K x Nc] -> fp16 [Nc x K]),
// zero counts. One kernel, segmented by linear thread id.
// ---------------------------------------------------------------------------
#define PREP_A  1280000                   // x: 10000*512/4 threads, 4 elems each
#define PREP_B  (512 * 512)               // W0t
#define PREP_C  (1024 * 512)              // W1t
#define PREP_D  (1024 * 256)              // W2t
#define PREP_E  N_NODES                   // zero counts
#define PREP_TOTAL (PREP_A + PREP_B + PREP_C + PREP_D + PREP_E)

__global__ void prep(const float* __restrict__ x,  _Float16* __restrict__ Xh,
                     const float* __restrict__ W0, _Float16* __restrict__ W0t,
                     const float* __restrict__ W1, _Float16* __restrict__ W1t,
                     const float* __restrict__ W2, _Float16* __restrict__ W2t,
                     int* __restrict__ counts) {
    int i = blockIdx.x * blockDim.x + threadIdx.x;
    if (i < PREP_A) {
        f32x4 v = *(const f32x4*)(x + (size_t)i * 4);
        half4 h;
        h[0] = (_Float16)v[0]; h[1] = (_Float16)v[1];
        h[2] = (_Float16)v[2]; h[3] = (_Float16)v[3];
        *(half4*)(Xh + (size_t)i * 4) = h;
        return;
    }
    i -= PREP_A;
    if (i < PREP_B) {                       // W0: 512x512
        int n = i >> 9, k = i & 511;
        W0t[i] = (_Float16)W0[(size_t)k * 512 + n];
        return;
    }
    i -= PREP_B;
    if (i < PREP_C) {                       // W1: 1024x512 -> W1t 512x1024
        int n = i >> 10, k = i & 1023;
        W1t[i] = (_Float16)W1[(size_t)k * 512 + n];
        return;
    }
    i -= PREP_C;
    if (i < PREP_D) {                       // W2: 1024x256 -> W2t 256x1024
        int n = i >> 10, k = i & 1023;
        W2t[i] = (_Float16)W2[(size_t)k * 256 + n];
        return;
    }
    i -= PREP_D;
    if (i < PREP_E) counts[i] = 0;
}

// ---------------------------------------------------------------------------
// CSR build
// ---------------------------------------------------------------------------
__global__ void hist_rows(const int* __restrict__ rows, int* __restrict__ counts, int E) {
    int i = blockIdx.x * blockDim.x + threadIdx.x;
    if (i < E) atomicAdd(&counts[rows[i]], 1);
}

__global__ void scan_rowptr(const int* __restrict__ counts,
                            int* __restrict__ row_ptr,
                            int* __restrict__ cursor, int n, int E) {
    __shared__ int part[256];
    const int t = threadIdx.x;
    const int chunk = (n + 255) / 256;
    const int lo = t * chunk;
    const int hi = min(n, lo + chunk);
    int s = 0;
    for (int i = lo; i < hi; ++i) s += counts[i];
    part[t] = s;
    __syncthreads();
    if (t == 0) {
        int run = 0;
        for (int i = 0; i < 256; ++i) { int v = part[i]; part[i] = run; run += v; }
    }
    __syncthreads();
    int run = part[t];
    for (int i = lo; i < hi; ++i) {
        row_ptr[i] = run;
        cursor[i]  = run;
        run += counts[i];
    }
    if (t == 0) row_ptr[n] = E;
}

// packed edge record: {col as int bits, val}
__global__ void scatter_edges(const int* __restrict__ rows,
                              const int* __restrict__ cols,
                              const float* __restrict__ vals,
                              int* __restrict__ cursor,
                              float2* __restrict__ ev, int E) {
    int i = blockIdx.x * blockDim.x + threadIdx.x;
    if (i < E) {
        int r = rows[i];
        int p = atomicAdd(&cursor[r], 1);
        ev[p] = make_float2(__int_as_float(cols[i]), vals[i]);
    }
}

// ---------------------------------------------------------------------------
// GEMM: C[M_PAD x Nc] = A[M_PAD x K] * Bt[Nc x K]^T. fp16 in/out, fp32 acc.
// Template tile TM x TN, BK=32, 4 waves in 2x2, double-buffered LDS with
// global_load_lds width=16 staging. TM=64 -> 632 blocks (2.5/CU).
// ---------------------------------------------------------------------------
template <int TM, int TN>
__global__ __launch_bounds__(256) void gemm_f16_t(
    const _Float16* __restrict__ A,
    const _Float16* __restrict__ Bt,
    _Float16* __restrict__ C,
    int K, int Nc)
{
    constexpr int WM = TM / 2;          // wave m-extent
    constexpr int WN = TN / 2;          // wave n-extent
    constexpr int MT = WM / 16;         // m-tiles per wave
    constexpr int NT = WN / 16;         // n-tiles per wave
    constexpr int NCHUNK = (TM + TN) / 16;   // 16-row staging chunks
    constexpr int CA = TM / 16;

    __shared__ _Float16 As[2][TM * 32];
    __shared__ _Float16 Bs[2][TN * 32];

    const int t    = threadIdx.x;
    const int lane = t & 63;
    const int wid  = t >> 6;
    const int wrow = wid >> 1;      // 0..1
    const int wcol = wid & 1;       // 0..1
    const int quad = lane >> 4;     // 0..3
    const int l15  = lane & 15;

    const int rowBase = blockIdx.y * TM;
    const int colBase = blockIdx.x * TN;

    const int rIn = lane >> 2;            // 0..15 within 16-row chunk
    const int cIn = (lane & 3) * 8;       // halves

    f32x4 acc[MT][NT];
#pragma unroll
    for (int m = 0; m < MT; ++m)
#pragma unroll
        for (int n = 0; n < NT; ++n)
            acc[m][n] = (f32x4){0.f, 0.f, 0.f, 0.f};

    auto stage = [&](int buf, int k0) {
#pragma unroll
        for (int p = 0; p < NCHUNK / 4; ++p) {
            const int c = wid + p * 4;            // wave-uniform chunk id
            if (c < CA) {
                const int r = c * 16 + rIn;
                async16(&A[(size_t)(rowBase + r) * K + k0 + cIn],
                        &As[buf][c * 512]);
            } else {
                const int r = (c - CA) * 16 + rIn;
                async16(&Bt[(size_t)(colBase + r) * K + k0 + cIn],
                        &Bs[buf][(c - CA) * 512]);
            }
        }
    };

    const int nk = K >> 5;
    stage(0, 0);

    for (int i = 0; i < nk; ++i) {
        __syncthreads();                          // drains stage(i)
        if (i + 1 < nk) stage((i + 1) & 1, (i + 1) << 5);

        const int b = i & 1;
        half8 af[MT], bf[NT];
#pragma unroll
        for (int m = 0; m < MT; ++m)
            af[m] = *(const half8*)(&As[b][(wrow * WM + m * 16 + l15) * 32 + quad * 8]);
#pragma unroll
        for (int n = 0; n < NT; ++n)
            bf[n] = *(const half8*)(&Bs[b][(wcol * WN + n * 16 + l15) * 32 + quad * 8]);

#pragma unroll
        for (int m = 0; m < MT; ++m)
#pragma unroll
            for (int n = 0; n < NT; ++n)
                acc[m][n] = __builtin_amdgcn_mfma_f32_16x16x32_f16(
                    af[m], bf[n], acc[m][n], 0, 0, 0);
    }

    // epilogue: C/D layout col = lane&15, row = quad*4 + reg
#pragma unroll
    for (int m = 0; m < MT; ++m) {
#pragma unroll
        for (int n = 0; n < NT; ++n) {
            int col = colBase + wcol * WN + n * 16 + l15;
#pragma unroll
            for (int r = 0; r < 4; ++r) {
                int row = rowBase + wrow * WM + m * 16 + quad * 4 + r;
                C[(size_t)row * Nc + col] = (_Float16)acc[m][n][r];
            }
        }
    }
}

// ---------------------------------------------------------------------------
// SpMM, feature-sliced: slice = 128 features (2.5 MB of S -> fits 4MB XCD L2).
// Block = 4 waves = 4 rows of one slice; blockIdx = slice + nslice*rowquad so
// a slice pins to XCDs {s, s+4, ...} via the blockIdx%8 round-robin.
// Wave: 4 edge-groups x 16 lanes; lane gathers 16B (8 feats) of S[col,slice];
// butterfly shfl_xor(16,32) reduces groups; fused bias(+relu+concat).
// ---------------------------------------------------------------------------
template <int D, bool FINAL>
__global__ __launch_bounds__(256) void spmm_slice(
    const int* __restrict__ row_ptr,
    const float2* __restrict__ ev,
    const _Float16* __restrict__ S,     // [M_PAD x D]
    const float* __restrict__ bias,     // [D]
    _Float16* __restrict__ Hout,        // [M_PAD x 2D] if !FINAL
    float* __restrict__ Fout)           // [N_NODES x D] if FINAL
{
    constexpr int NS = D / 128;         // slices
    const int s  = blockIdx.x & (NS - 1);
    const int rq = blockIdx.x / NS;
    const int w  = threadIdx.x >> 6;    // wave -> row within quad
    const int row = rq * 4 + w;
    const int lane = threadIdx.x & 63;
    const int g = lane >> 4;            // edge-group 0..3
    const int l = lane & 15;            // feature-lane

    const int r0 = row_ptr[row];
    const int r1 = row_ptr[row + 1];

    float acc[8];
#pragma unroll
    for (int j = 0; j < 8; ++j) acc[j] = 0.f;

    const _Float16* __restrict__ Sb = S + s * 128 + l * 8;

    int e = r0 + g;
    // unroll 2 (per-group stride 4 -> pair stride 8)
    for (; e + 4 < r1; e += 8) {
        float2 p0 = ev[e];
        float2 p1 = ev[e + 4];
        half8 s0 = *(const half8*)(Sb + (size_t)__float_as_int(p0.x) * D);
        half8 s1 = *(const half8*)(Sb + (size_t)__float_as_int(p1.x) * D);
#pragma unroll
        for (int j = 0; j < 8; ++j) {
            acc[j] += p0.y * (float)s0[j];
            acc[j] += p1.y * (float)s1[j];
        }
    }
    if (e < r1) {
        float2 p0 = ev[e];
        half8 s0 = *(const half8*)(Sb + (size_t)__float_as_int(p0.x) * D);
#pragma unroll
        for (int j = 0; j < 8; ++j) acc[j] += p0.y * (float)s0[j];
    }

    // butterfly across the 4 edge-groups (lanes xor 16, xor 32)
#pragma unroll
    for (int j = 0; j < 8; ++j) {
        acc[j] += __shfl_xor(acc[j], 16, 64);
        acc[j] += __shfl_xor(acc[j], 32, 64);
    }

    const int f0 = s * 128 + l * 8;
    f32x4 b0 = *(const f32x4*)(bias + f0);
    f32x4 b1 = *(const f32x4*)(bias + f0 + 4);

    if constexpr (FINAL) {
        if (g == 0) {
            f32x4 o = {acc[0] + b0[0], acc[1] + b0[1], acc[2] + b0[2], acc[3] + b0[3]};
            *(f32x4*)(Fout + (size_t)row * D + f0) = o;
        } else if (g == 1) {
            f32x4 o = {acc[4] + b1[0], acc[5] + b1[1], acc[6] + b1[2], acc[7] + b1[3]};
            *(f32x4*)(Fout + (size_t)row * D + f0 + 4) = o;
        }
    } else {
        float v[8];
#pragma unroll
        for (int j = 0; j < 4; ++j) v[j] = acc[j] + b0[j];
#pragma unroll
        for (int j = 0; j < 4; ++j) v[4 + j] = acc[4 + j] + b1[j];
        if (g == 0) {                   // relu half
            half8 h;
#pragma unroll
            for (int j = 0; j < 8; ++j) h[j] = (_Float16)(v[j] > 0.f ? v[j] : 0.f);
            *(half8*)(Hout + (size_t)row * (2 * D) + f0) = h;
        } else if (g == 1) {            // raw half
            half8 h;
#pragma unroll
            for (int j = 0; j < 8; ++j) h[j] = (_Float16)v[j];
            *(half8*)(Hout + (size_t)row * (2 * D) + D + f0) = h;
        }
    }
}

// ---------------------------------------------------------------------------
static inline char* alignp(char* p, size_t a) {
    return (char*)(((uintptr_t)p + a - 1) & ~(uintptr_t)(a - 1));
}

extern "C" void kernel_launch(void* const* d_in, const int* in_sizes, int n_in,
                              void* d_out, int out_size, void* d_ws, size_t ws_size,
                              hipStream_t stream) {
    const float* x        = (const float*)d_in[0];   // [10000 x 512]
    const int*   edge_row = (const int*)d_in[1];     // [E]
    const int*   edge_col = (const int*)d_in[2];     // [E]
    const float* edge_val = (const float*)d_in[3];   // [E]
    const float* W0 = (const float*)d_in[4];         // [512 x 512]
    const float* W1 = (const float*)d_in[5];         // [1024 x 512]
    const float* W2 = (const float*)d_in[6];         // [1024 x 256]
    const float* b0 = (const float*)d_in[7];
    const float* b1 = (const float*)d_in[8];
    const float* b2 = (const float*)d_in[9];
    float* out = (float*)d_out;                      // [10000 x 256]

    const int E = N_EDGES;

    // ---- workspace carve-up ----
    char* p = (char*)d_ws;
    _Float16* Xh  = (_Float16*)alignp(p, 256);  p = (char*)(Xh  + (size_t)M_PAD * 512);
    _Float16* S   = (_Float16*)alignp(p, 256);  p = (char*)(S   + (size_t)M_PAD * 512);
    _Float16* H   = (_Float16*)alignp(p, 256);  p = (char*)(H   + (size_t)M_PAD * 1024);
    _Float16* W0t = (_Float16*)alignp(p, 256);  p = (char*)(W0t + (size_t)512 * 512);
    _Float16* W1t = (_Float16*)alignp(p, 256);  p = (char*)(W1t + (size_t)512 * 1024);
    _Float16* W2t = (_Float16*)alignp(p, 256);  p = (char*)(W2t + (size_t)256 * 1024);
    int*    counts  = (int*)alignp(p, 256);     p = (char*)(counts  + N_NODES);
    int*    row_ptr = (int*)alignp(p, 256);     p = (char*)(row_ptr + N_NODES + 1);
    int*    cursor  = (int*)alignp(p, 256);     p = (char*)(cursor  + N_NODES);
    float2* ev      = (float2*)alignp(p, 256);  p = (char*)(ev      + E);

    // ---- prep (conv + transposes + zero counts), then CSR build ----
    prep<<<(PREP_TOTAL + 255) / 256, 256, 0, stream>>>(x, Xh, W0, W0t, W1, W1t,
                                                       W2, W2t, counts);
    hist_rows<<<(E + 255) / 256, 256, 0, stream>>>(edge_row, counts, E);
    scan_rowptr<<<1, 256, 0, stream>>>(counts, row_ptr, cursor, N_NODES, E);
    scatter_edges<<<(E + 255) / 256, 256, 0, stream>>>(edge_row, edge_col, edge_val,
                                                       cursor, ev, E);

    // ---- layer 0 ----
    gemm_f16_t<64, 128><<<dim3(512 / 128, M_PAD / 64), 256, 0, stream>>>(Xh, W0t, S, 512, 512);
    spmm_slice<512, false><<<(N_NODES / 4) * 4, 256, 0, stream>>>(row_ptr, ev, S, b0, H, nullptr);
    // ---- layer 1 ----
    gemm_f16_t<64, 128><<<dim3(512 / 128, M_PAD / 64), 256, 0, stream>>>(H, W1t, S, 1024, 512);
    spmm_slice<512, false><<<(N_NODES / 4) * 4, 256, 0, stream>>>(row_ptr, ev, S, b1, H, nullptr);
    // ---- layer 2 ----
    gemm_f16_t<64, 64><<<dim3(256 / 64, M_PAD / 64), 256, 0, stream>>>(H, W2t, S, 1024, 256);
    spmm_slice<256, true><<<(N_NODES / 4) * 2, 256, 0, stream>>>(row_ptr, ev, S, b2, nullptr, out);
}